// Round 4
// baseline (261.822 us; speedup 1.0000x reference)
//
#include <hip/hip_runtime.h>
#include <hip/hip_bf16.h>

#define BF16 __hip_bfloat16

typedef __bf16 bf16x8 __attribute__((ext_vector_type(8)));
typedef float floatx4 __attribute__((ext_vector_type(4)));

struct __align__(8) bf4 { BF16 a, b, c, d; };

__device__ __forceinline__ void glds16(const void* g, void* l) {
    __builtin_amdgcn_global_load_lds(
        (const __attribute__((address_space(1))) void*)g,
        (__attribute__((address_space(3))) void*)l, 16, 0, 0);
}

// ---------------- fused transpose + fp32->bf16 convert (3 matrices, 1 launch) ----
// feat: [2][256][13600] -> [2][13600][256]; w1: [12544][1024] -> [1024][12544];
// w2: [1024][1024] -> [1024][1024]^T. 32x32 tiles, block = 256 threads.
__global__ __launch_bounds__(256) void transpose_all(const float* __restrict__ features,
                                                     const float* __restrict__ fc1_w,
                                                     const float* __restrict__ fc2_w,
                                                     BF16* __restrict__ featT,
                                                     BF16* __restrict__ w1t,
                                                     BF16* __restrict__ w2t) {
    __shared__ float tile[32][33];
    int bid = blockIdx.x;
    const float* ip;
    BF16* op;
    int R, C, cx, cy;
    if (bid < 6800) {
        int z = bid / 3400, r = bid - z * 3400;
        cx = r % 425; cy = r / 425;
        R = 256; C = 13600;
        ip = features + (size_t)z * 256 * 13600;
        op = featT + (size_t)z * 256 * 13600;
    } else if (bid < 19344) {
        int r = bid - 6800;
        cx = r & 31; cy = r >> 5;
        R = 12544; C = 1024;
        ip = fc1_w; op = w1t;
    } else {
        int r = bid - 19344;
        cx = r & 31; cy = r >> 5;
        R = 1024; C = 1024;
        ip = fc2_w; op = w2t;
    }
    int tx = threadIdx.x & 31, ty = threadIdx.x >> 5;
    int r0 = cy << 5, c0 = cx << 5;
#pragma unroll
    for (int i = 0; i < 4; ++i)
        tile[ty + i * 8][tx] = ip[(size_t)(r0 + ty + i * 8) * C + c0 + tx];
    __syncthreads();
#pragma unroll
    for (int i = 0; i < 4; ++i)
        op[(size_t)(c0 + ty + i * 8) * R + r0 + tx] = __float2bfloat16(tile[tx][ty + i * 8]);
}

// ---------------- ROI align (phase-split, vectorized) ----------------
__global__ __launch_bounds__(256) void roi_align_k(const BF16* __restrict__ featT,
                                                   const float* __restrict__ boxes,
                                                   const int* __restrict__ roi_batch,
                                                   BF16* __restrict__ feats) {
    __shared__ __align__(16) int   s_off[196][4];
    __shared__ __align__(16) float s_w[196][4];
    __shared__ BF16 lbuf[12544];
    int roi = blockIdx.x;
    int t = threadIdx.x;
    BF16* orow = feats + (size_t)roi * 12544;
    if (roi >= 1000) {
        uint* o4 = (uint*)orow;
        for (int i = t; i < 6272; i += 256) o4[i] = 0u;
        return;
    }
    int b = roi_batch[roi];

    if (t < 196) {
        float x1 = boxes[roi * 4 + 0] * 0.125f;
        float y1 = boxes[roi * 4 + 1] * 0.125f;
        float x2 = boxes[roi * 4 + 2] * 0.125f;
        float y2 = boxes[roi * 4 + 3] * 0.125f;
        float bw = fmaxf(x2 - x1, 1.0f) * (1.0f / 7.0f);
        float bh = fmaxf(y2 - y1, 1.0f) * (1.0f / 7.0f);
        int cell = t >> 2, s = t & 3;
        int oy = cell / 7, ox = cell - oy * 7;
        int sy = s >> 1, sx = s & 1;
        float yc = y1 + ((float)oy + ((float)sy + 0.5f) * 0.5f) * bh;
        float xc = x1 + ((float)ox + ((float)sx + 0.5f) * 0.5f) * bw;
        yc = fminf(fmaxf(yc, 0.0f), 99.0f);
        xc = fminf(fmaxf(xc, 0.0f), 135.0f);
        float y0f = floorf(yc), x0f = floorf(xc);
        int y0 = (int)y0f, x0 = (int)x0f;
        int y1i = min(y0 + 1, 99), x1i = min(x0 + 1, 135);
        float ly = yc - y0f, lx = xc - x0f;
        s_w[t][0] = (1.0f - ly) * (1.0f - lx) * 0.25f;
        s_w[t][1] = (1.0f - ly) * lx * 0.25f;
        s_w[t][2] = ly * (1.0f - lx) * 0.25f;
        s_w[t][3] = ly * lx * 0.25f;
        s_off[t][0] = (y0 * 136 + x0) * 256;
        s_off[t][1] = (y0 * 136 + x1i) * 256;
        s_off[t][2] = (y1i * 136 + x0) * 256;
        s_off[t][3] = (y1i * 136 + x1i) * 256;
    }
    __syncthreads();

    int lane = t & 63, cg = t >> 6;
    const BF16* fb = featT + (size_t)b * (100 * 136 * 256) + lane * 4;
    int cbase = lane * 4;
    for (int cell = cg; cell < 49; cell += 4) {
        float a0 = 0.f, a1 = 0.f, a2 = 0.f, a3 = 0.f;
#pragma unroll
        for (int s = 0; s < 4; ++s) {
            int p = cell * 4 + s;
#pragma unroll
            for (int tap = 0; tap < 4; ++tap) {
                float w = s_w[p][tap];
                bf4 v = *(const bf4*)(fb + s_off[p][tap]);
                a0 += w * __bfloat162float(v.a);
                a1 += w * __bfloat162float(v.b);
                a2 += w * __bfloat162float(v.c);
                a3 += w * __bfloat162float(v.d);
            }
        }
        lbuf[(cbase + 0) * 49 + cell] = __float2bfloat16(a0);
        lbuf[(cbase + 1) * 49 + cell] = __float2bfloat16(a1);
        lbuf[(cbase + 2) * 49 + cell] = __float2bfloat16(a2);
        lbuf[(cbase + 3) * 49 + cell] = __float2bfloat16(a3);
    }
    __syncthreads();
    uint* o4 = (uint*)orow;
    const uint* l4 = (const uint*)lbuf;
    for (int i = t; i < 6272; i += 256) o4[i] = l4[i];
}

// ---------------- split-K bf16 MFMA GEMM, 128x128 tile, dbuf, bf16 partials ----
// A bf16 [1024][K], Bt bf16 [1024][K], P bf16 [S][1024][1024].
// grid (8, 8, S); chunk = K/S, chunk % 32 == 0.
__global__ __launch_bounds__(256) void gemm_splitk(const BF16* __restrict__ A,
                                                   const BF16* __restrict__ Bt,
                                                   BF16* __restrict__ P,
                                                   int K, int chunk) {
    __shared__ char lds[2][2][8192];
    int w = threadIdx.x >> 6, l = threadIdx.x & 63;
    int wm = w & 1, wn = w >> 1;
    int tm = blockIdx.y, tn = blockIdx.x, s = blockIdx.z;
    int k0 = s * chunk;

    floatx4 acc[4][4];
#pragma unroll
    for (int i = 0; i < 4; ++i)
#pragma unroll
        for (int j = 0; j < 4; ++j) acc[i][j] = (floatx4){0.f, 0.f, 0.f, 0.f};

    const size_t strideA = (size_t)K * 2;
    const char* gA = (const char*)A + (size_t)(tm * 128 + w * 16 + (l >> 2)) * strideA
                     + (size_t)k0 * 2 + (size_t)(l & 3) * 16;
    const char* gB = (const char*)Bt + (size_t)(tn * 128 + w * 16 + (l >> 2)) * strideA
                     + (size_t)k0 * 2 + (size_t)(l & 3) * 16;
    size_t rowJump = 64 * strideA;

    int aoff = (wm * 64 + (l & 15)) * 64 + (l >> 4) * 16;
    int boff = (wn * 64 + (l & 15)) * 64 + (l >> 4) * 16;

    int nIter = chunk >> 5;

    glds16(gA, &lds[0][0][w * 1024]);
    glds16(gA + rowJump, &lds[0][0][w * 1024 + 4096]);
    glds16(gB, &lds[0][1][w * 1024]);
    glds16(gB + rowJump, &lds[0][1][w * 1024 + 4096]);
    __syncthreads();

    for (int kb = 0; kb < nIter; ++kb) {
        int cur = kb & 1;
        if (kb + 1 < nIter) {
            const char* pa = gA + (size_t)(kb + 1) * 64;
            const char* pb = gB + (size_t)(kb + 1) * 64;
            char* la = &lds[cur ^ 1][0][w * 1024];
            char* lb = &lds[cur ^ 1][1][w * 1024];
            glds16(pa, la);
            glds16(pa + rowJump, la + 4096);
            glds16(pb, lb);
            glds16(pb + rowJump, lb + 4096);
        }
        const char* bufA = lds[cur][0];
        const char* bufB = lds[cur][1];
        bf16x8 af[4], bf[4];
#pragma unroll
        for (int mi = 0; mi < 4; ++mi) af[mi] = *(const bf16x8*)(bufA + aoff + mi * 1024);
#pragma unroll
        for (int ni = 0; ni < 4; ++ni) bf[ni] = *(const bf16x8*)(bufB + boff + ni * 1024);
#pragma unroll
        for (int mi = 0; mi < 4; ++mi)
#pragma unroll
            for (int ni = 0; ni < 4; ++ni)
                acc[mi][ni] = __builtin_amdgcn_mfma_f32_16x16x32_bf16(af[mi], bf[ni], acc[mi][ni], 0, 0, 0);
        __syncthreads();
    }

    int q = l >> 4, c = l & 15;
    size_t base = (size_t)s << 20;
#pragma unroll
    for (int mi = 0; mi < 4; ++mi) {
        int rowG = tm * 128 + wm * 64 + mi * 16 + q * 4;
#pragma unroll
        for (int ni = 0; ni < 4; ++ni) {
            int colG = tn * 128 + wn * 64 + ni * 16 + c;
#pragma unroll
            for (int r = 0; r < 4; ++r)
                P[base + (size_t)(rowG + r) * 1024 + colG] = __float2bfloat16(acc[mi][ni][r]);
        }
    }
}

// ---------------- reduce bf16 partials + bias + ReLU -> bf16 ----------------
__global__ __launch_bounds__(256) void reduce_k(const BF16* __restrict__ P,
                                                const float* __restrict__ bias,
                                                BF16* __restrict__ out,
                                                int S) {
    int i = blockIdx.x * 256 + threadIdx.x;
    float a = bias[i & 1023];
    for (int s = 0; s < S; ++s) a += __bfloat162float(P[((size_t)s << 20) + i]);
    a = fmaxf(a, 0.0f);
    out[i] = __float2bfloat16(a);
}

// ---------------- heads: fc2-reduce fused + softmax + decode ----------------
// P2 bf16 [S2][1024][1024] partials of fc2; h2 = relu(sum + fc2_b) computed on the fly.
__global__ __launch_bounds__(256) void head_k(const BF16* __restrict__ P2,
                                              const float* __restrict__ fc2_b,
                                              const float* __restrict__ cls_w,
                                              const float* __restrict__ cls_b,
                                              const float* __restrict__ bbox_w,
                                              const float* __restrict__ bbox_b,
                                              const float* __restrict__ boxes,
                                              float* __restrict__ out, int S2) {
    int w = threadIdx.x >> 6, l = threadIdx.x & 63;
    int roi = blockIdx.x * 4 + w;
    if (roi >= 1000) return;
    float acc[10];
#pragma unroll
    for (int j = 0; j < 10; ++j) acc[j] = 0.0f;
    const BF16* pr = P2 + (size_t)roi * 1024;
    for (int k = l; k < 1024; k += 64) {
        float h = fc2_b[k];
        for (int s = 0; s < S2; ++s) h += __bfloat162float(pr[((size_t)s << 20) + k]);
        h = fmaxf(h, 0.0f);
        acc[0] += h * cls_w[k * 2 + 0];
        acc[1] += h * cls_w[k * 2 + 1];
#pragma unroll
        for (int j = 0; j < 8; ++j) acc[2 + j] += h * bbox_w[k * 8 + j];
    }
#pragma unroll
    for (int j = 0; j < 10; ++j) {
#pragma unroll
        for (int off = 32; off > 0; off >>= 1) acc[j] += __shfl_down(acc[j], off);
    }
    if (l == 0) {
        float s0 = acc[0] + cls_b[0], s1 = acc[1] + cls_b[1];
        float m = fmaxf(s0, s1);
        float e0 = expf(s0 - m), e1 = expf(s1 - m);
        float inv = 1.0f / (e0 + e1);

        float bx1 = boxes[roi * 4 + 0], by1 = boxes[roi * 4 + 1];
        float bx2 = boxes[roi * 4 + 2], by2 = boxes[roi * 4 + 3];
        float pw = bx2 - bx1, ph = by2 - by1;
        float cx = bx1 + 0.5f * pw, cy = by1 + 0.5f * ph;
        const float CLAMPV = 4.135166556742356f;
        float* orow = out + roi * 10;
#pragma unroll
        for (int cl = 0; cl < 2; ++cl) {
            float dx = (acc[2 + cl * 4 + 0] + bbox_b[cl * 4 + 0]) * 0.1f;
            float dy = (acc[2 + cl * 4 + 1] + bbox_b[cl * 4 + 1]) * 0.1f;
            float dw = fminf((acc[2 + cl * 4 + 2] + bbox_b[cl * 4 + 2]) * 0.2f, CLAMPV);
            float dh = fminf((acc[2 + cl * 4 + 3] + bbox_b[cl * 4 + 3]) * 0.2f, CLAMPV);
            float pcx = dx * pw + cx, pcy = dy * ph + cy;
            float pww = expf(dw) * pw, phh = expf(dh) * ph;
            orow[cl * 4 + 0] = fminf(fmaxf(pcx - 0.5f * pww, 0.0f), 1088.0f);
            orow[cl * 4 + 1] = fminf(fmaxf(pcy - 0.5f * phh, 0.0f), 800.0f);
            orow[cl * 4 + 2] = fminf(fmaxf(pcx + 0.5f * pww, 0.0f), 1088.0f);
            orow[cl * 4 + 3] = fminf(fmaxf(pcy + 0.5f * phh, 0.0f), 800.0f);
        }
        orow[8] = e0 * inv;
        orow[9] = e1 * inv;
    }
}

extern "C" void kernel_launch(void* const* d_in, const int* in_sizes, int n_in,
                              void* d_out, int out_size, void* d_ws, size_t ws_size,
                              hipStream_t stream) {
    const float* features = (const float*)d_in[0];
    const float* boxes    = (const float*)d_in[1];
    const int*   roi_b    = (const int*)d_in[2];
    const float* fc1_w    = (const float*)d_in[3];
    const float* fc1_b    = (const float*)d_in[4];
    const float* fc2_w    = (const float*)d_in[5];
    const float* fc2_b    = (const float*)d_in[6];
    const float* cls_w    = (const float*)d_in[7];
    const float* cls_b    = (const float*)d_in[8];
    const float* bbox_w   = (const float*)d_in[9];
    const float* bbox_b   = (const float*)d_in[10];
    float* out = (float*)d_out;

    char* ws = (char*)d_ws;
    BF16* featT = (BF16*)(ws + 0);           // [0, 13,926,400)
    BF16* w1t   = (BF16*)(ws + 13926400);    // [.., 39,616,512)
    BF16* w2t   = (BF16*)(ws + 39616512);    // [.., 41,713,664)
    BF16* feats = (BF16*)(ws + 41713664);    // [.., 67,403,776)
    BF16* h1    = (BF16*)(ws + 67403776);    // [.., 69,500,928)
    BF16* P1    = (BF16*)(ws + 69500928);    // S1*2MB; S1=14 -> ends 98,861,056 (< proven 105.1 MB)
    BF16* P2    = (BF16*)(ws + 0);           // 8*2MB = 16.8 MB; reuses dead featT/w1t region

    int S1 = (ws_size >= (size_t)69500928 + (size_t)14 * 2097152) ? 14 : 8;
    int S2 = 8;

    transpose_all<<<20368, 256, 0, stream>>>(features, fc1_w, fc2_w, featT, w1t, w2t);

    roi_align_k<<<1024, 256, 0, stream>>>(featT, boxes, roi_b, feats);

    gemm_splitk<<<dim3(8, 8, S1), 256, 0, stream>>>(feats, w1t, P1, 12544, 12544 / S1);
    reduce_k<<<4096, 256, 0, stream>>>(P1, fc1_b, h1, S1);

    gemm_splitk<<<dim3(8, 8, S2), 256, 0, stream>>>(h1, w2t, P2, 1024, 1024 / S2);

    head_k<<<250, 256, 0, stream>>>(P2, fc2_b, cls_w, cls_b, bbox_w, bbox_b, boxes, out, S2);
}

// Round 5
// 254.721 us; speedup vs baseline: 1.0279x; 1.0279x over previous
//
#include <hip/hip_runtime.h>
#include <hip/hip_bf16.h>

#define BF16 __hip_bfloat16

typedef __bf16 bf16x8 __attribute__((ext_vector_type(8)));
typedef float floatx4 __attribute__((ext_vector_type(4)));

struct __align__(8) bf4 { BF16 a, b, c, d; };

__device__ __forceinline__ void glds16(const void* g, void* l) {
    __builtin_amdgcn_global_load_lds(
        (const __attribute__((address_space(1))) void*)g,
        (__attribute__((address_space(3))) void*)l, 16, 0, 0);
}

// ---------------- fused transpose + fp32->bf16 convert (3 matrices, 1 launch) ----
__global__ __launch_bounds__(256) void transpose_all(const float* __restrict__ features,
                                                     const float* __restrict__ fc1_w,
                                                     const float* __restrict__ fc2_w,
                                                     BF16* __restrict__ featT,
                                                     BF16* __restrict__ w1t,
                                                     BF16* __restrict__ w2t) {
    __shared__ float tile[32][33];
    int bid = blockIdx.x;
    const float* ip;
    BF16* op;
    int R, C, cx, cy;
    if (bid < 6800) {
        int z = bid / 3400, r = bid - z * 3400;
        cx = r % 425; cy = r / 425;
        R = 256; C = 13600;
        ip = features + (size_t)z * 256 * 13600;
        op = featT + (size_t)z * 256 * 13600;
    } else if (bid < 19344) {
        int r = bid - 6800;
        cx = r & 31; cy = r >> 5;
        R = 12544; C = 1024;
        ip = fc1_w; op = w1t;
    } else {
        int r = bid - 19344;
        cx = r & 31; cy = r >> 5;
        R = 1024; C = 1024;
        ip = fc2_w; op = w2t;
    }
    int tx = threadIdx.x & 31, ty = threadIdx.x >> 5;
    int r0 = cy << 5, c0 = cx << 5;
#pragma unroll
    for (int i = 0; i < 4; ++i)
        tile[ty + i * 8][tx] = ip[(size_t)(r0 + ty + i * 8) * C + c0 + tx];
    __syncthreads();
#pragma unroll
    for (int i = 0; i < 4; ++i)
        op[(size_t)(c0 + ty + i * 8) * R + r0 + tx] = __float2bfloat16(tile[tx][ty + i * 8]);
}

// ---------------- ROI align (phase-split, vectorized) ----------------
__global__ __launch_bounds__(256) void roi_align_k(const BF16* __restrict__ featT,
                                                   const float* __restrict__ boxes,
                                                   const int* __restrict__ roi_batch,
                                                   BF16* __restrict__ feats) {
    __shared__ __align__(16) int   s_off[196][4];
    __shared__ __align__(16) float s_w[196][4];
    __shared__ BF16 lbuf[12544];
    int roi = blockIdx.x;
    int t = threadIdx.x;
    BF16* orow = feats + (size_t)roi * 12544;
    if (roi >= 1000) {
        uint* o4 = (uint*)orow;
        for (int i = t; i < 6272; i += 256) o4[i] = 0u;
        return;
    }
    int b = roi_batch[roi];

    if (t < 196) {
        float x1 = boxes[roi * 4 + 0] * 0.125f;
        float y1 = boxes[roi * 4 + 1] * 0.125f;
        float x2 = boxes[roi * 4 + 2] * 0.125f;
        float y2 = boxes[roi * 4 + 3] * 0.125f;
        float bw = fmaxf(x2 - x1, 1.0f) * (1.0f / 7.0f);
        float bh = fmaxf(y2 - y1, 1.0f) * (1.0f / 7.0f);
        int cell = t >> 2, s = t & 3;
        int oy = cell / 7, ox = cell - oy * 7;
        int sy = s >> 1, sx = s & 1;
        float yc = y1 + ((float)oy + ((float)sy + 0.5f) * 0.5f) * bh;
        float xc = x1 + ((float)ox + ((float)sx + 0.5f) * 0.5f) * bw;
        yc = fminf(fmaxf(yc, 0.0f), 99.0f);
        xc = fminf(fmaxf(xc, 0.0f), 135.0f);
        float y0f = floorf(yc), x0f = floorf(xc);
        int y0 = (int)y0f, x0 = (int)x0f;
        int y1i = min(y0 + 1, 99), x1i = min(x0 + 1, 135);
        float ly = yc - y0f, lx = xc - x0f;
        s_w[t][0] = (1.0f - ly) * (1.0f - lx) * 0.25f;
        s_w[t][1] = (1.0f - ly) * lx * 0.25f;
        s_w[t][2] = ly * (1.0f - lx) * 0.25f;
        s_w[t][3] = ly * lx * 0.25f;
        s_off[t][0] = (y0 * 136 + x0) * 256;
        s_off[t][1] = (y0 * 136 + x1i) * 256;
        s_off[t][2] = (y1i * 136 + x0) * 256;
        s_off[t][3] = (y1i * 136 + x1i) * 256;
    }
    __syncthreads();

    int lane = t & 63, cg = t >> 6;
    const BF16* fb = featT + (size_t)b * (100 * 136 * 256) + lane * 4;
    int cbase = lane * 4;
    for (int cell = cg; cell < 49; cell += 4) {
        float a0 = 0.f, a1 = 0.f, a2 = 0.f, a3 = 0.f;
#pragma unroll
        for (int s = 0; s < 4; ++s) {
            int p = cell * 4 + s;
#pragma unroll
            for (int tap = 0; tap < 4; ++tap) {
                float w = s_w[p][tap];
                bf4 v = *(const bf4*)(fb + s_off[p][tap]);
                a0 += w * __bfloat162float(v.a);
                a1 += w * __bfloat162float(v.b);
                a2 += w * __bfloat162float(v.c);
                a3 += w * __bfloat162float(v.d);
            }
        }
        lbuf[(cbase + 0) * 49 + cell] = __float2bfloat16(a0);
        lbuf[(cbase + 1) * 49 + cell] = __float2bfloat16(a1);
        lbuf[(cbase + 2) * 49 + cell] = __float2bfloat16(a2);
        lbuf[(cbase + 3) * 49 + cell] = __float2bfloat16(a3);
    }
    __syncthreads();
    uint* o4 = (uint*)orow;
    const uint* l4 = (const uint*)lbuf;
    for (int i = t; i < 6272; i += 256) o4[i] = l4[i];
}

// ---- split-K bf16 MFMA GEMM, 128x128 tile, BK=64, XOR-swizzled LDS, fp32 partials ----
// A bf16 [1024][K], Bt bf16 [1024][K], P fp32 [S][1024][1024].
// grid (8, 8, S); chunk = K/S, chunk % 64 == 0. 256 threads = 4 waves (2x2).
// Staging: LDS row = 128 B = 8 chunks of 16 B; slot s of row r holds global
// chunk s ^ (r&7) (XOR swizzle -> 2-way bank aliasing on fragment reads = free).
__global__ __launch_bounds__(256) void gemm_splitk(const BF16* __restrict__ A,
                                                   const BF16* __restrict__ Bt,
                                                   float* __restrict__ P,
                                                   int K, int chunk) {
    __shared__ char lds[2][2][16384];  // [buf][A/B][128 rows x 128 B]
    int w = threadIdx.x >> 6, l = threadIdx.x & 63;
    int wm = w & 1, wn = w >> 1;
    int tm = blockIdx.y, tn = blockIdx.x, s = blockIdx.z;
    int k0 = s * chunk;

    floatx4 acc[4][4];
#pragma unroll
    for (int i = 0; i < 4; ++i)
#pragma unroll
        for (int j = 0; j < 4; ++j) acc[i][j] = (floatx4){0.f, 0.f, 0.f, 0.f};

    const size_t strideA = (size_t)K * 2;  // bytes per row
    int r8 = l >> 3;                 // row within 8-row issue group
    int g8 = (l & 7) ^ r8;           // XOR-swizzled global chunk for this lane
    // wave w stages rows [w*32, w*32+32) in 4 issues of 8 rows
    const char* gA = (const char*)A + (size_t)(tm * 128 + w * 32 + r8) * strideA
                     + (size_t)k0 * 2 + (size_t)g8 * 16;
    const char* gB = (const char*)Bt + (size_t)(tn * 128 + w * 32 + r8) * strideA
                     + (size_t)k0 * 2 + (size_t)g8 * 16;

    // fragment read offsets: row*128 + ((kk*4+q)^(c&7))*16
    int c = l & 15, q = l >> 4;
    int xa0 = ((0 * 4 + q) ^ (c & 7)) * 16;
    int xa1 = ((1 * 4 + q) ^ (c & 7)) * 16;
    int abase = (wm * 64 + c) * 128;
    int bbase = (wn * 64 + c) * 128;

    int nIter = chunk >> 6;

    // preload iter 0 into buf 0 (4 issues x 8 rows per wave per matrix)
#pragma unroll
    for (int i = 0; i < 4; ++i) {
        glds16(gA + (size_t)(i * 8) * strideA, &lds[0][0][w * 4096 + i * 1024]);
        glds16(gB + (size_t)(i * 8) * strideA, &lds[0][1][w * 4096 + i * 1024]);
    }
    __syncthreads();

    for (int kb = 0; kb < nIter; ++kb) {
        int cur = kb & 1;
        if (kb + 1 < nIter) {
            size_t ko = (size_t)(kb + 1) * 128;
#pragma unroll
            for (int i = 0; i < 4; ++i) {
                glds16(gA + (size_t)(i * 8) * strideA + ko, &lds[cur ^ 1][0][w * 4096 + i * 1024]);
                glds16(gB + (size_t)(i * 8) * strideA + ko, &lds[cur ^ 1][1][w * 4096 + i * 1024]);
            }
        }
        const char* bufA = lds[cur][0];
        const char* bufB = lds[cur][1];
#pragma unroll
        for (int kk = 0; kk < 2; ++kk) {
            int xo = kk ? xa1 : xa0;
            bf16x8 af[4], bfr[4];
#pragma unroll
            for (int mi = 0; mi < 4; ++mi) af[mi] = *(const bf16x8*)(bufA + abase + mi * 2048 + xo);
#pragma unroll
            for (int ni = 0; ni < 4; ++ni) bfr[ni] = *(const bf16x8*)(bufB + bbase + ni * 2048 + xo);
#pragma unroll
            for (int mi = 0; mi < 4; ++mi)
#pragma unroll
                for (int ni = 0; ni < 4; ++ni)
                    acc[mi][ni] = __builtin_amdgcn_mfma_f32_16x16x32_bf16(af[mi], bfr[ni], acc[mi][ni], 0, 0, 0);
        }
        __syncthreads();
    }

    // D layout: col = lane&15, row = (lane>>4)*4 + reg
    size_t base = (size_t)s << 20;
#pragma unroll
    for (int mi = 0; mi < 4; ++mi) {
        int rowG = tm * 128 + wm * 64 + mi * 16 + q * 4;
#pragma unroll
        for (int ni = 0; ni < 4; ++ni) {
            int colG = tn * 128 + wn * 64 + ni * 16 + c;
#pragma unroll
            for (int r = 0; r < 4; ++r)
                P[base + (size_t)(rowG + r) * 1024 + colG] = acc[mi][ni][r];
        }
    }
}

// ---------------- reduce fp32 partials + bias + ReLU -> bf16 ----------------
__global__ __launch_bounds__(256) void reduce_k(const float* __restrict__ P,
                                                const float* __restrict__ bias,
                                                BF16* __restrict__ out,
                                                int S) {
    int i = blockIdx.x * 256 + threadIdx.x;
    float a = bias[i & 1023];
    for (int s = 0; s < S; ++s) a += P[((size_t)s << 20) + i];
    a = fmaxf(a, 0.0f);
    out[i] = __float2bfloat16(a);
}

// ---------------- heads: fc2-reduce fused + softmax + decode ----------------
__global__ __launch_bounds__(256) void head_k(const float* __restrict__ P2,
                                              const float* __restrict__ fc2_b,
                                              const float* __restrict__ cls_w,
                                              const float* __restrict__ cls_b,
                                              const float* __restrict__ bbox_w,
                                              const float* __restrict__ bbox_b,
                                              const float* __restrict__ boxes,
                                              float* __restrict__ out, int S2) {
    int w = threadIdx.x >> 6, l = threadIdx.x & 63;
    int roi = blockIdx.x * 4 + w;
    if (roi >= 1000) return;
    float acc[10];
#pragma unroll
    for (int j = 0; j < 10; ++j) acc[j] = 0.0f;
    const float* pr = P2 + (size_t)roi * 1024;
    for (int k = l; k < 1024; k += 64) {
        float h = fc2_b[k];
        for (int s = 0; s < S2; ++s) h += pr[((size_t)s << 20) + k];
        h = fmaxf(h, 0.0f);
        acc[0] += h * cls_w[k * 2 + 0];
        acc[1] += h * cls_w[k * 2 + 1];
#pragma unroll
        for (int j = 0; j < 8; ++j) acc[2 + j] += h * bbox_w[k * 8 + j];
    }
#pragma unroll
    for (int j = 0; j < 10; ++j) {
#pragma unroll
        for (int off = 32; off > 0; off >>= 1) acc[j] += __shfl_down(acc[j], off);
    }
    if (l == 0) {
        float s0 = acc[0] + cls_b[0], s1 = acc[1] + cls_b[1];
        float m = fmaxf(s0, s1);
        float e0 = expf(s0 - m), e1 = expf(s1 - m);
        float inv = 1.0f / (e0 + e1);

        float bx1 = boxes[roi * 4 + 0], by1 = boxes[roi * 4 + 1];
        float bx2 = boxes[roi * 4 + 2], by2 = boxes[roi * 4 + 3];
        float pw = bx2 - bx1, ph = by2 - by1;
        float cx = bx1 + 0.5f * pw, cy = by1 + 0.5f * ph;
        const float CLAMPV = 4.135166556742356f;
        float* orow = out + roi * 10;
#pragma unroll
        for (int cl = 0; cl < 2; ++cl) {
            float dx = (acc[2 + cl * 4 + 0] + bbox_b[cl * 4 + 0]) * 0.1f;
            float dy = (acc[2 + cl * 4 + 1] + bbox_b[cl * 4 + 1]) * 0.1f;
            float dw = fminf((acc[2 + cl * 4 + 2] + bbox_b[cl * 4 + 2]) * 0.2f, CLAMPV);
            float dh = fminf((acc[2 + cl * 4 + 3] + bbox_b[cl * 4 + 3]) * 0.2f, CLAMPV);
            float pcx = dx * pw + cx, pcy = dy * ph + cy;
            float pww = expf(dw) * pw, phh = expf(dh) * ph;
            orow[cl * 4 + 0] = fminf(fmaxf(pcx - 0.5f * pww, 0.0f), 1088.0f);
            orow[cl * 4 + 1] = fminf(fmaxf(pcy - 0.5f * phh, 0.0f), 800.0f);
            orow[cl * 4 + 2] = fminf(fmaxf(pcx + 0.5f * pww, 0.0f), 1088.0f);
            orow[cl * 4 + 3] = fminf(fmaxf(pcy + 0.5f * phh, 0.0f), 800.0f);
        }
        orow[8] = e0 * inv;
        orow[9] = e1 * inv;
    }
}

extern "C" void kernel_launch(void* const* d_in, const int* in_sizes, int n_in,
                              void* d_out, int out_size, void* d_ws, size_t ws_size,
                              hipStream_t stream) {
    const float* features = (const float*)d_in[0];
    const float* boxes    = (const float*)d_in[1];
    const int*   roi_b    = (const int*)d_in[2];
    const float* fc1_w    = (const float*)d_in[3];
    const float* fc1_b    = (const float*)d_in[4];
    const float* fc2_w    = (const float*)d_in[5];
    const float* fc2_b    = (const float*)d_in[6];
    const float* cls_w    = (const float*)d_in[7];
    const float* cls_b    = (const float*)d_in[8];
    const float* bbox_w   = (const float*)d_in[9];
    const float* bbox_b   = (const float*)d_in[10];
    float* out = (float*)d_out;

    char* ws = (char*)d_ws;
    BF16* featT = (BF16*)(ws + 0);           // [0, 13,926,400)
    BF16* w1t   = (BF16*)(ws + 13926400);    // [.., 39,616,512)
    BF16* w2t   = (BF16*)(ws + 39616512);    // [.., 41,713,664)
    BF16* feats = (BF16*)(ws + 41713664);    // [.., 67,403,776)
    BF16* h1    = (BF16*)(ws + 67403776);    // [.., 69,500,928)
    float* P1   = (float*)(ws + 69500928);   // 7 * 4 MB -> ends 98,861,056 (< proven 105.1 MB)
    float* P2   = (float*)(ws + 0);          // 8 * 4 MB = 33.5 MB; reuses dead featT/w1t

    int S1 = 7;   // 12544 = 7 * 1792, 1792 = 28 * 64
    int S2 = 8;   // 1024 = 8 * 128, 128 = 2 * 64

    transpose_all<<<20368, 256, 0, stream>>>(features, fc1_w, fc2_w, featT, w1t, w2t);

    roi_align_k<<<1024, 256, 0, stream>>>(featT, boxes, roi_b, feats);

    gemm_splitk<<<dim3(8, 8, S1), 256, 0, stream>>>(feats, w1t, P1, 12544, 12544 / S1);
    reduce_k<<<4096, 256, 0, stream>>>(P1, fc1_b, h1, S1);

    gemm_splitk<<<dim3(8, 8, S2), 256, 0, stream>>>(h1, w2t, P2, 1024, 1024 / S2);

    head_k<<<250, 256, 0, stream>>>(P2, fc2_b, cls_w, cls_b, bbox_w, bbox_b, boxes, out, S2);
}

// Round 6
// 219.682 us; speedup vs baseline: 1.1918x; 1.1595x over previous
//
#include <hip/hip_runtime.h>
#include <hip/hip_bf16.h>

#define BF16 __hip_bfloat16

typedef __bf16 bf16x8 __attribute__((ext_vector_type(8)));
typedef float floatx4 __attribute__((ext_vector_type(4)));

struct __align__(8) bf4 { BF16 a, b, c, d; };

__device__ __forceinline__ void glds16(const void* g, void* l) {
    __builtin_amdgcn_global_load_lds(
        (const __attribute__((address_space(1))) void*)g,
        (__attribute__((address_space(3))) void*)l, 16, 0, 0);
}

// ---------------- fused transpose + fp32->bf16 convert (3 matrices, 1 launch) ----
__global__ __launch_bounds__(256) void transpose_all(const float* __restrict__ features,
                                                     const float* __restrict__ fc1_w,
                                                     const float* __restrict__ fc2_w,
                                                     BF16* __restrict__ featT,
                                                     BF16* __restrict__ w1t,
                                                     BF16* __restrict__ w2t) {
    __shared__ float tile[32][33];
    int bid = blockIdx.x;
    const float* ip;
    BF16* op;
    int R, C, cx, cy;
    if (bid < 6800) {
        int z = bid / 3400, r = bid - z * 3400;
        cx = r % 425; cy = r / 425;
        R = 256; C = 13600;
        ip = features + (size_t)z * 256 * 13600;
        op = featT + (size_t)z * 256 * 13600;
    } else if (bid < 19344) {
        int r = bid - 6800;
        cx = r & 31; cy = r >> 5;
        R = 12544; C = 1024;
        ip = fc1_w; op = w1t;
    } else {
        int r = bid - 19344;
        cx = r & 31; cy = r >> 5;
        R = 1024; C = 1024;
        ip = fc2_w; op = w2t;
    }
    int tx = threadIdx.x & 31, ty = threadIdx.x >> 5;
    int r0 = cy << 5, c0 = cx << 5;
#pragma unroll
    for (int i = 0; i < 4; ++i)
        tile[ty + i * 8][tx] = ip[(size_t)(r0 + ty + i * 8) * C + c0 + tx];
    __syncthreads();
#pragma unroll
    for (int i = 0; i < 4; ++i)
        op[(size_t)(c0 + ty + i * 8) * R + r0 + tx] = __float2bfloat16(tile[tx][ty + i * 8]);
}

// ---------------- ROI align (phase-split, vectorized) ----------------
__global__ __launch_bounds__(256) void roi_align_k(const BF16* __restrict__ featT,
                                                   const float* __restrict__ boxes,
                                                   const int* __restrict__ roi_batch,
                                                   BF16* __restrict__ feats) {
    __shared__ __align__(16) int   s_off[196][4];
    __shared__ __align__(16) float s_w[196][4];
    __shared__ BF16 lbuf[12544];
    int roi = blockIdx.x;
    int t = threadIdx.x;
    BF16* orow = feats + (size_t)roi * 12544;
    if (roi >= 1000) {
        uint* o4 = (uint*)orow;
        for (int i = t; i < 6272; i += 256) o4[i] = 0u;
        return;
    }
    int b = roi_batch[roi];

    if (t < 196) {
        float x1 = boxes[roi * 4 + 0] * 0.125f;
        float y1 = boxes[roi * 4 + 1] * 0.125f;
        float x2 = boxes[roi * 4 + 2] * 0.125f;
        float y2 = boxes[roi * 4 + 3] * 0.125f;
        float bw = fmaxf(x2 - x1, 1.0f) * (1.0f / 7.0f);
        float bh = fmaxf(y2 - y1, 1.0f) * (1.0f / 7.0f);
        int cell = t >> 2, s = t & 3;
        int oy = cell / 7, ox = cell - oy * 7;
        int sy = s >> 1, sx = s & 1;
        float yc = y1 + ((float)oy + ((float)sy + 0.5f) * 0.5f) * bh;
        float xc = x1 + ((float)ox + ((float)sx + 0.5f) * 0.5f) * bw;
        yc = fminf(fmaxf(yc, 0.0f), 99.0f);
        xc = fminf(fmaxf(xc, 0.0f), 135.0f);
        float y0f = floorf(yc), x0f = floorf(xc);
        int y0 = (int)y0f, x0 = (int)x0f;
        int y1i = min(y0 + 1, 99), x1i = min(x0 + 1, 135);
        float ly = yc - y0f, lx = xc - x0f;
        s_w[t][0] = (1.0f - ly) * (1.0f - lx) * 0.25f;
        s_w[t][1] = (1.0f - ly) * lx * 0.25f;
        s_w[t][2] = ly * (1.0f - lx) * 0.25f;
        s_w[t][3] = ly * lx * 0.25f;
        s_off[t][0] = (y0 * 136 + x0) * 256;
        s_off[t][1] = (y0 * 136 + x1i) * 256;
        s_off[t][2] = (y1i * 136 + x0) * 256;
        s_off[t][3] = (y1i * 136 + x1i) * 256;
    }
    __syncthreads();

    int lane = t & 63, cg = t >> 6;
    const BF16* fb = featT + (size_t)b * (100 * 136 * 256) + lane * 4;
    int cbase = lane * 4;
    for (int cell = cg; cell < 49; cell += 4) {
        float a0 = 0.f, a1 = 0.f, a2 = 0.f, a3 = 0.f;
#pragma unroll
        for (int s = 0; s < 4; ++s) {
            int p = cell * 4 + s;
#pragma unroll
            for (int tap = 0; tap < 4; ++tap) {
                float w = s_w[p][tap];
                bf4 v = *(const bf4*)(fb + s_off[p][tap]);
                a0 += w * __bfloat162float(v.a);
                a1 += w * __bfloat162float(v.b);
                a2 += w * __bfloat162float(v.c);
                a3 += w * __bfloat162float(v.d);
            }
        }
        lbuf[(cbase + 0) * 49 + cell] = __float2bfloat16(a0);
        lbuf[(cbase + 1) * 49 + cell] = __float2bfloat16(a1);
        lbuf[(cbase + 2) * 49 + cell] = __float2bfloat16(a2);
        lbuf[(cbase + 3) * 49 + cell] = __float2bfloat16(a3);
    }
    __syncthreads();
    uint* o4 = (uint*)orow;
    const uint* l4 = (const uint*)lbuf;
    for (int i = t; i < 6272; i += 256) o4[i] = l4[i];
}

// ---- split-K bf16 MFMA GEMM, 128x128 tile, BK=64, XOR-swizzled LDS, fp32 partials ----
__global__ __launch_bounds__(256) void gemm_splitk(const BF16* __restrict__ A,
                                                   const BF16* __restrict__ Bt,
                                                   float* __restrict__ P,
                                                   int K, int chunk) {
    __shared__ char lds[2][2][16384];
    int w = threadIdx.x >> 6, l = threadIdx.x & 63;
    int wm = w & 1, wn = w >> 1;
    int tm = blockIdx.y, tn = blockIdx.x, s = blockIdx.z;
    int k0 = s * chunk;

    floatx4 acc[4][4];
#pragma unroll
    for (int i = 0; i < 4; ++i)
#pragma unroll
        for (int j = 0; j < 4; ++j) acc[i][j] = (floatx4){0.f, 0.f, 0.f, 0.f};

    const size_t strideA = (size_t)K * 2;
    int r8 = l >> 3;
    int g8 = (l & 7) ^ r8;
    const char* gA = (const char*)A + (size_t)(tm * 128 + w * 32 + r8) * strideA
                     + (size_t)k0 * 2 + (size_t)g8 * 16;
    const char* gB = (const char*)Bt + (size_t)(tn * 128 + w * 32 + r8) * strideA
                     + (size_t)k0 * 2 + (size_t)g8 * 16;

    int c = l & 15, q = l >> 4;
    int xa0 = ((0 * 4 + q) ^ (c & 7)) * 16;
    int xa1 = ((1 * 4 + q) ^ (c & 7)) * 16;
    int abase = (wm * 64 + c) * 128;
    int bbase = (wn * 64 + c) * 128;

    int nIter = chunk >> 6;

#pragma unroll
    for (int i = 0; i < 4; ++i) {
        glds16(gA + (size_t)(i * 8) * strideA, &lds[0][0][w * 4096 + i * 1024]);
        glds16(gB + (size_t)(i * 8) * strideA, &lds[0][1][w * 4096 + i * 1024]);
    }
    __syncthreads();

    for (int kb = 0; kb < nIter; ++kb) {
        int cur = kb & 1;
        if (kb + 1 < nIter) {
            size_t ko = (size_t)(kb + 1) * 128;
#pragma unroll
            for (int i = 0; i < 4; ++i) {
                glds16(gA + (size_t)(i * 8) * strideA + ko, &lds[cur ^ 1][0][w * 4096 + i * 1024]);
                glds16(gB + (size_t)(i * 8) * strideA + ko, &lds[cur ^ 1][1][w * 4096 + i * 1024]);
            }
        }
        const char* bufA = lds[cur][0];
        const char* bufB = lds[cur][1];
#pragma unroll
        for (int kk = 0; kk < 2; ++kk) {
            int xo = kk ? xa1 : xa0;
            bf16x8 af[4], bfr[4];
#pragma unroll
            for (int mi = 0; mi < 4; ++mi) af[mi] = *(const bf16x8*)(bufA + abase + mi * 2048 + xo);
#pragma unroll
            for (int ni = 0; ni < 4; ++ni) bfr[ni] = *(const bf16x8*)(bufB + bbase + ni * 2048 + xo);
#pragma unroll
            for (int mi = 0; mi < 4; ++mi)
#pragma unroll
                for (int ni = 0; ni < 4; ++ni)
                    acc[mi][ni] = __builtin_amdgcn_mfma_f32_16x16x32_bf16(af[mi], bfr[ni], acc[mi][ni], 0, 0, 0);
        }
        __syncthreads();
    }

    size_t base = (size_t)s << 20;
#pragma unroll
    for (int mi = 0; mi < 4; ++mi) {
        int rowG = tm * 128 + wm * 64 + mi * 16 + q * 4;
#pragma unroll
        for (int ni = 0; ni < 4; ++ni) {
            int colG = tn * 128 + wn * 64 + ni * 16 + c;
#pragma unroll
            for (int r = 0; r < 4; ++r)
                P[base + (size_t)(rowG + r) * 1024 + colG] = acc[mi][ni][r];
        }
    }
}

// ---------------- reduce fp32 partials + bias + ReLU -> bf16 ----------------
__global__ __launch_bounds__(256) void reduce_k(const float* __restrict__ P,
                                                const float* __restrict__ bias,
                                                BF16* __restrict__ out,
                                                int S) {
    int i = blockIdx.x * 256 + threadIdx.x;
    float a = bias[i & 1023];
    for (int s = 0; s < S; ++s) a += P[((size_t)s << 20) + i];
    a = fmaxf(a, 0.0f);
    out[i] = __float2bfloat16(a);
}

// ---------------- heads: per-ROI block, fused fc2 reduce + softmax + decode ----
// P2 fp32 [S2][1024][1024]; grid = 1000 blocks; thread t owns k in [4t, 4t+4).
__global__ __launch_bounds__(256) void head_k(const float* __restrict__ P2,
                                              const float* __restrict__ fc2_b,
                                              const float* __restrict__ cls_w,
                                              const float* __restrict__ cls_b,
                                              const float* __restrict__ bbox_w,
                                              const float* __restrict__ bbox_b,
                                              const float* __restrict__ boxes,
                                              float* __restrict__ out, int S2) {
    __shared__ float red[4][10];
    int roi = blockIdx.x;
    int t = threadIdx.x, w = t >> 6, l = t & 63;
    int k4 = t * 4;

    // h[0..3] = relu(fc2_b + sum_s P2slice) for k = k4..k4+3 — all float4 loads
    floatx4 h = *(const floatx4*)(fc2_b + k4);
    const float* pbase = P2 + (size_t)roi * 1024 + k4;
    for (int s = 0; s < S2; ++s) {
        floatx4 p = *(const floatx4*)(pbase + ((size_t)s << 20));
        h.x += p.x; h.y += p.y; h.z += p.z; h.w += p.w;
    }
    h.x = fmaxf(h.x, 0.f); h.y = fmaxf(h.y, 0.f); h.z = fmaxf(h.z, 0.f); h.w = fmaxf(h.w, 0.f);

    float acc[10];
#pragma unroll
    for (int j = 0; j < 10; ++j) acc[j] = 0.0f;
    // cls_w [1024][2]: 8 contiguous floats for this thread
    floatx4 c0 = *(const floatx4*)(cls_w + k4 * 2);
    floatx4 c1 = *(const floatx4*)(cls_w + k4 * 2 + 4);
    acc[0] = h.x * c0.x + h.y * c0.z + h.z * c1.x + h.w * c1.z;
    acc[1] = h.x * c0.y + h.y * c0.w + h.z * c1.y + h.w * c1.w;
    // bbox_w [1024][8]: 32 contiguous floats
    const float* bw = bbox_w + k4 * 8;
#pragma unroll
    for (int kk = 0; kk < 4; ++kk) {
        float hv = (kk == 0) ? h.x : (kk == 1) ? h.y : (kk == 2) ? h.z : h.w;
        floatx4 b0 = *(const floatx4*)(bw + kk * 8);
        floatx4 b1 = *(const floatx4*)(bw + kk * 8 + 4);
        acc[2] += hv * b0.x; acc[3] += hv * b0.y; acc[4] += hv * b0.z; acc[5] += hv * b0.w;
        acc[6] += hv * b1.x; acc[7] += hv * b1.y; acc[8] += hv * b1.z; acc[9] += hv * b1.w;
    }
#pragma unroll
    for (int j = 0; j < 10; ++j) {
#pragma unroll
        for (int off = 32; off > 0; off >>= 1) acc[j] += __shfl_down(acc[j], off);
    }
    if (l == 0) {
#pragma unroll
        for (int j = 0; j < 10; ++j) red[w][j] = acc[j];
    }
    __syncthreads();
    if (t == 0) {
        float f[10];
#pragma unroll
        for (int j = 0; j < 10; ++j) f[j] = red[0][j] + red[1][j] + red[2][j] + red[3][j];
        float s0 = f[0] + cls_b[0], s1 = f[1] + cls_b[1];
        float m = fmaxf(s0, s1);
        float e0 = expf(s0 - m), e1 = expf(s1 - m);
        float inv = 1.0f / (e0 + e1);

        float bx1 = boxes[roi * 4 + 0], by1 = boxes[roi * 4 + 1];
        float bx2 = boxes[roi * 4 + 2], by2 = boxes[roi * 4 + 3];
        float pw = bx2 - bx1, ph = by2 - by1;
        float cx = bx1 + 0.5f * pw, cy = by1 + 0.5f * ph;
        const float CLAMPV = 4.135166556742356f;
        float* orow = out + roi * 10;
#pragma unroll
        for (int cl = 0; cl < 2; ++cl) {
            float dx = (f[2 + cl * 4 + 0] + bbox_b[cl * 4 + 0]) * 0.1f;
            float dy = (f[2 + cl * 4 + 1] + bbox_b[cl * 4 + 1]) * 0.1f;
            float dw = fminf((f[2 + cl * 4 + 2] + bbox_b[cl * 4 + 2]) * 0.2f, CLAMPV);
            float dh = fminf((f[2 + cl * 4 + 3] + bbox_b[cl * 4 + 3]) * 0.2f, CLAMPV);
            float pcx = dx * pw + cx, pcy = dy * ph + cy;
            float pww = expf(dw) * pw, phh = expf(dh) * ph;
            orow[cl * 4 + 0] = fminf(fmaxf(pcx - 0.5f * pww, 0.0f), 1088.0f);
            orow[cl * 4 + 1] = fminf(fmaxf(pcy - 0.5f * phh, 0.0f), 800.0f);
            orow[cl * 4 + 2] = fminf(fmaxf(pcx + 0.5f * pww, 0.0f), 1088.0f);
            orow[cl * 4 + 3] = fminf(fmaxf(pcy + 0.5f * phh, 0.0f), 800.0f);
        }
        orow[8] = e0 * inv;
        orow[9] = e1 * inv;
    }
}

extern "C" void kernel_launch(void* const* d_in, const int* in_sizes, int n_in,
                              void* d_out, int out_size, void* d_ws, size_t ws_size,
                              hipStream_t stream) {
    const float* features = (const float*)d_in[0];
    const float* boxes    = (const float*)d_in[1];
    const int*   roi_b    = (const int*)d_in[2];
    const float* fc1_w    = (const float*)d_in[3];
    const float* fc1_b    = (const float*)d_in[4];
    const float* fc2_w    = (const float*)d_in[5];
    const float* fc2_b    = (const float*)d_in[6];
    const float* cls_w    = (const float*)d_in[7];
    const float* cls_b    = (const float*)d_in[8];
    const float* bbox_w   = (const float*)d_in[9];
    const float* bbox_b   = (const float*)d_in[10];
    float* out = (float*)d_out;

    char* ws = (char*)d_ws;
    BF16* featT = (BF16*)(ws + 0);           // [0, 13,926,400)
    BF16* w1t   = (BF16*)(ws + 13926400);    // [.., 39,616,512)
    BF16* w2t   = (BF16*)(ws + 39616512);    // [.., 41,713,664)
    BF16* feats = (BF16*)(ws + 41713664);    // [.., 67,403,776)
    BF16* h1    = (BF16*)(ws + 67403776);    // [.., 69,500,928)
    float* P1   = (float*)(ws + 69500928);   // 7 * 4 MB -> ends 98,861,056 (proven safe R4)
    float* P2   = (float*)(ws + 0);          // 4 * 4 MB = 16.8 MB; reuses dead featT

    int S1 = 7;   // 12544 = 7 * 1792, 1792 = 28 * 64
    int S2 = 4;   // 1024 = 4 * 256, 256 = 4 * 64

    transpose_all<<<20368, 256, 0, stream>>>(features, fc1_w, fc2_w, featT, w1t, w2t);

    roi_align_k<<<1024, 256, 0, stream>>>(featT, boxes, roi_b, feats);

    gemm_splitk<<<dim3(8, 8, S1), 256, 0, stream>>>(feats, w1t, P1, 12544, 12544 / S1);
    reduce_k<<<4096, 256, 0, stream>>>(P1, fc1_b, h1, S1);

    gemm_splitk<<<dim3(8, 8, S2), 256, 0, stream>>>(h1, w2t, P2, 1024, 1024 / S2);

    head_k<<<1000, 256, 0, stream>>>(P2, fc2_b, cls_w, cls_b, bbox_w, bbox_b, boxes, out, S2);
}

// Round 7
// 215.981 us; speedup vs baseline: 1.2122x; 1.0171x over previous
//
#include <hip/hip_runtime.h>
#include <hip/hip_bf16.h>

#define BF16 __hip_bfloat16

typedef __bf16 bf16x8 __attribute__((ext_vector_type(8)));
typedef float floatx4 __attribute__((ext_vector_type(4)));
typedef int intx4 __attribute__((ext_vector_type(4)));

// ---------------- fused transpose + fp32->bf16 convert (3 matrices, 1 launch) ----
__global__ __launch_bounds__(256) void transpose_all(const float* __restrict__ features,
                                                     const float* __restrict__ fc1_w,
                                                     const float* __restrict__ fc2_w,
                                                     BF16* __restrict__ featT,
                                                     BF16* __restrict__ w1t,
                                                     BF16* __restrict__ w2t) {
    __shared__ float tile[32][33];
    int bid = blockIdx.x;
    const float* ip;
    BF16* op;
    int R, C, cx, cy;
    if (bid < 6800) {
        int z = bid / 3400, r = bid - z * 3400;
        cx = r % 425; cy = r / 425;
        R = 256; C = 13600;
        ip = features + (size_t)z * 256 * 13600;
        op = featT + (size_t)z * 256 * 13600;
    } else if (bid < 19344) {
        int r = bid - 6800;
        cx = r & 31; cy = r >> 5;
        R = 12544; C = 1024;
        ip = fc1_w; op = w1t;
    } else {
        int r = bid - 19344;
        cx = r & 31; cy = r >> 5;
        R = 1024; C = 1024;
        ip = fc2_w; op = w2t;
    }
    int tx = threadIdx.x & 31, ty = threadIdx.x >> 5;
    int r0 = cy << 5, c0 = cx << 5;
#pragma unroll
    for (int i = 0; i < 4; ++i)
        tile[ty + i * 8][tx] = ip[(size_t)(r0 + ty + i * 8) * C + c0 + tx];
    __syncthreads();
#pragma unroll
    for (int i = 0; i < 4; ++i)
        op[(size_t)(c0 + ty + i * 8) * R + r0 + tx] = __float2bfloat16(tile[tx][ty + i * 8]);
}

// ---------------- ROI align (phase-split, 16B vector taps) ----------------
// featT bf16 [B][100][136][256]; thread = (cell-group t>>5, 8-ch block t&31).
__global__ __launch_bounds__(256) void roi_align_k(const BF16* __restrict__ featT,
                                                   const float* __restrict__ boxes,
                                                   const int* __restrict__ roi_batch,
                                                   BF16* __restrict__ feats) {
    __shared__ __align__(16) int   s_off[196][4];
    __shared__ __align__(16) float s_w[196][4];
    __shared__ BF16 lbuf[12544];
    int roi = blockIdx.x;
    int t = threadIdx.x;
    BF16* orow = feats + (size_t)roi * 12544;
    if (roi >= 1000) {
        uint4* o4 = (uint4*)orow;
        uint4 z = {0u, 0u, 0u, 0u};
        for (int i = t; i < 1568; i += 256) o4[i] = z;
        return;
    }
    int b = roi_batch[roi];

    if (t < 196) {
        float x1 = boxes[roi * 4 + 0] * 0.125f;
        float y1 = boxes[roi * 4 + 1] * 0.125f;
        float x2 = boxes[roi * 4 + 2] * 0.125f;
        float y2 = boxes[roi * 4 + 3] * 0.125f;
        float bw = fmaxf(x2 - x1, 1.0f) * (1.0f / 7.0f);
        float bh = fmaxf(y2 - y1, 1.0f) * (1.0f / 7.0f);
        int cell = t >> 2, s = t & 3;
        int oy = cell / 7, ox = cell - oy * 7;
        int sy = s >> 1, sx = s & 1;
        float yc = y1 + ((float)oy + ((float)sy + 0.5f) * 0.5f) * bh;
        float xc = x1 + ((float)ox + ((float)sx + 0.5f) * 0.5f) * bw;
        yc = fminf(fmaxf(yc, 0.0f), 99.0f);
        xc = fminf(fmaxf(xc, 0.0f), 135.0f);
        float y0f = floorf(yc), x0f = floorf(xc);
        int y0 = (int)y0f, x0 = (int)x0f;
        int y1i = min(y0 + 1, 99), x1i = min(x0 + 1, 135);
        float ly = yc - y0f, lx = xc - x0f;
        s_w[t][0] = (1.0f - ly) * (1.0f - lx) * 0.25f;
        s_w[t][1] = (1.0f - ly) * lx * 0.25f;
        s_w[t][2] = ly * (1.0f - lx) * 0.25f;
        s_w[t][3] = ly * lx * 0.25f;
        s_off[t][0] = (y0 * 136 + x0) * 256;
        s_off[t][1] = (y0 * 136 + x1i) * 256;
        s_off[t][2] = (y1i * 136 + x0) * 256;
        s_off[t][3] = (y1i * 136 + x1i) * 256;
    }
    __syncthreads();

    int cb = t & 31, g = t >> 5;   // ch = cb*8..cb*8+7; cell group g (8 groups)
    const BF16* fb = featT + (size_t)b * (100 * 136 * 256) + cb * 8;
    int chbase = cb * 8;
    for (int cell = g; cell < 49; cell += 8) {
        float a[8];
#pragma unroll
        for (int j = 0; j < 8; ++j) a[j] = 0.0f;
#pragma unroll
        for (int s = 0; s < 4; ++s) {
            int p = cell * 4 + s;
#pragma unroll
            for (int tap = 0; tap < 4; ++tap) {
                float w = s_w[p][tap];
                bf16x8 v = *(const bf16x8*)(fb + s_off[p][tap]);
#pragma unroll
                for (int j = 0; j < 8; ++j) a[j] += w * (float)v[j];
            }
        }
#pragma unroll
        for (int j = 0; j < 8; ++j)
            lbuf[(chbase + j) * 49 + cell] = __float2bfloat16(a[j]);
    }
    __syncthreads();
    uint4* o4 = (uint4*)orow;
    const uint4* l4 = (const uint4*)lbuf;
    for (int i = t; i < 1568; i += 256) o4[i] = l4[i];
}

// ---- split-K bf16 MFMA GEMM, 128x128 tile, BK=64, register-prefetch pipeline ----
// A bf16 [1024][K], Bt bf16 [1024][K], P fp32 [S][1024][1024].
// grid (8, 8, S); chunk = K/S, chunk % 64 == 0. 256 threads = 4 waves (2x2).
// Per iter: global_load_dwordx4 -> VGPR (next tile), MFMA on cur LDS buffer,
// ds_write VGPR -> other buffer, one barrier. vmcnt wait lands AFTER the MFMAs.
// XOR swizzle: slot s of LDS row r holds global chunk s^(r&7).
__global__ __launch_bounds__(256) void gemm_splitk(const BF16* __restrict__ A,
                                                   const BF16* __restrict__ Bt,
                                                   float* __restrict__ P,
                                                   int K, int chunk) {
    __shared__ char lds[2][2][16384];
    int w = threadIdx.x >> 6, l = threadIdx.x & 63;
    int wm = w & 1, wn = w >> 1;
    int tm = blockIdx.y, tn = blockIdx.x, s = blockIdx.z;
    int k0 = s * chunk;

    floatx4 acc[4][4];
#pragma unroll
    for (int i = 0; i < 4; ++i)
#pragma unroll
        for (int j = 0; j < 4; ++j) acc[i][j] = (floatx4){0.f, 0.f, 0.f, 0.f};

    const size_t strideA = (size_t)K * 2;
    int r8 = l >> 3;
    int g8 = (l & 7) ^ r8;       // XOR-swizzled global chunk for this lane
    const char* gA = (const char*)A + (size_t)(tm * 128 + w * 32 + r8) * strideA
                     + (size_t)k0 * 2 + (size_t)g8 * 16;
    const char* gB = (const char*)Bt + (size_t)(tn * 128 + w * 32 + r8) * strideA
                     + (size_t)k0 * 2 + (size_t)g8 * 16;
    int lw = w * 4096 + l * 16;  // this thread's LDS slot base (i stride 1024)

    int c = l & 15, q = l >> 4;
    int xa0 = ((0 * 4 + q) ^ (c & 7)) * 16;
    int xa1 = ((1 * 4 + q) ^ (c & 7)) * 16;
    int abase = (wm * 64 + c) * 128;
    int bbase = (wn * 64 + c) * 128;

    int nIter = chunk >> 6;

    intx4 pa[4], pb[4];
    // prologue: load + write iter 0 into buf 0
#pragma unroll
    for (int i = 0; i < 4; ++i) {
        pa[i] = *(const intx4*)(gA + (size_t)(i * 8) * strideA);
        pb[i] = *(const intx4*)(gB + (size_t)(i * 8) * strideA);
    }
#pragma unroll
    for (int i = 0; i < 4; ++i) {
        *(intx4*)(&lds[0][0][lw + i * 1024]) = pa[i];
        *(intx4*)(&lds[0][1][lw + i * 1024]) = pb[i];
    }
    __syncthreads();

    for (int kb = 0; kb < nIter; ++kb) {
        int cur = kb & 1;
        bool more = (kb + 1 < nIter);
        if (more) {
            size_t ko = (size_t)(kb + 1) * 128;
#pragma unroll
            for (int i = 0; i < 4; ++i) {
                pa[i] = *(const intx4*)(gA + (size_t)(i * 8) * strideA + ko);
                pb[i] = *(const intx4*)(gB + (size_t)(i * 8) * strideA + ko);
            }
        }
        const char* bufA = lds[cur][0];
        const char* bufB = lds[cur][1];
#pragma unroll
        for (int kk = 0; kk < 2; ++kk) {
            int xo = kk ? xa1 : xa0;
            bf16x8 af[4], bfr[4];
#pragma unroll
            for (int mi = 0; mi < 4; ++mi) af[mi] = *(const bf16x8*)(bufA + abase + mi * 2048 + xo);
#pragma unroll
            for (int ni = 0; ni < 4; ++ni) bfr[ni] = *(const bf16x8*)(bufB + bbase + ni * 2048 + xo);
#pragma unroll
            for (int mi = 0; mi < 4; ++mi)
#pragma unroll
                for (int ni = 0; ni < 4; ++ni)
                    acc[mi][ni] = __builtin_amdgcn_mfma_f32_16x16x32_bf16(af[mi], bfr[ni], acc[mi][ni], 0, 0, 0);
        }
        if (more) {
            char* nA = &lds[cur ^ 1][0][lw];
            char* nB = &lds[cur ^ 1][1][lw];
#pragma unroll
            for (int i = 0; i < 4; ++i) {
                *(intx4*)(nA + i * 1024) = pa[i];   // vmcnt wait sits here, after MFMAs
                *(intx4*)(nB + i * 1024) = pb[i];
            }
        }
        __syncthreads();
    }

    size_t base = (size_t)s << 20;
#pragma unroll
    for (int mi = 0; mi < 4; ++mi) {
        int rowG = tm * 128 + wm * 64 + mi * 16 + q * 4;
#pragma unroll
        for (int ni = 0; ni < 4; ++ni) {
            int colG = tn * 128 + wn * 64 + ni * 16 + c;
#pragma unroll
            for (int r = 0; r < 4; ++r)
                P[base + (size_t)(rowG + r) * 1024 + colG] = acc[mi][ni][r];
        }
    }
}

// ---------------- reduce fp32 partials + bias + ReLU -> bf16 ----------------
__global__ __launch_bounds__(256) void reduce_k(const float* __restrict__ P,
                                                const float* __restrict__ bias,
                                                BF16* __restrict__ out,
                                                int S) {
    int i = blockIdx.x * 256 + threadIdx.x;
    float a = bias[i & 1023];
    for (int s = 0; s < S; ++s) a += P[((size_t)s << 20) + i];
    a = fmaxf(a, 0.0f);
    out[i] = __float2bfloat16(a);
}

// ---------------- heads: per-ROI block, fused fc2 reduce + softmax + decode ----
__global__ __launch_bounds__(256) void head_k(const float* __restrict__ P2,
                                              const float* __restrict__ fc2_b,
                                              const float* __restrict__ cls_w,
                                              const float* __restrict__ cls_b,
                                              const float* __restrict__ bbox_w,
                                              const float* __restrict__ bbox_b,
                                              const float* __restrict__ boxes,
                                              float* __restrict__ out, int S2) {
    __shared__ float red[4][10];
    int roi = blockIdx.x;
    int t = threadIdx.x, w = t >> 6, l = t & 63;
    int k4 = t * 4;

    floatx4 h = *(const floatx4*)(fc2_b + k4);
    const float* pbase = P2 + (size_t)roi * 1024 + k4;
    for (int s = 0; s < S2; ++s) {
        floatx4 p = *(const floatx4*)(pbase + ((size_t)s << 20));
        h.x += p.x; h.y += p.y; h.z += p.z; h.w += p.w;
    }
    h.x = fmaxf(h.x, 0.f); h.y = fmaxf(h.y, 0.f); h.z = fmaxf(h.z, 0.f); h.w = fmaxf(h.w, 0.f);

    float acc[10];
#pragma unroll
    for (int j = 0; j < 10; ++j) acc[j] = 0.0f;
    floatx4 c0 = *(const floatx4*)(cls_w + k4 * 2);
    floatx4 c1 = *(const floatx4*)(cls_w + k4 * 2 + 4);
    acc[0] = h.x * c0.x + h.y * c0.z + h.z * c1.x + h.w * c1.z;
    acc[1] = h.x * c0.y + h.y * c0.w + h.z * c1.y + h.w * c1.w;
    const float* bw = bbox_w + k4 * 8;
#pragma unroll
    for (int kk = 0; kk < 4; ++kk) {
        float hv = (kk == 0) ? h.x : (kk == 1) ? h.y : (kk == 2) ? h.z : h.w;
        floatx4 b0 = *(const floatx4*)(bw + kk * 8);
        floatx4 b1 = *(const floatx4*)(bw + kk * 8 + 4);
        acc[2] += hv * b0.x; acc[3] += hv * b0.y; acc[4] += hv * b0.z; acc[5] += hv * b0.w;
        acc[6] += hv * b1.x; acc[7] += hv * b1.y; acc[8] += hv * b1.z; acc[9] += hv * b1.w;
    }
#pragma unroll
    for (int j = 0; j < 10; ++j) {
#pragma unroll
        for (int off = 32; off > 0; off >>= 1) acc[j] += __shfl_down(acc[j], off);
    }
    if (l == 0) {
#pragma unroll
        for (int j = 0; j < 10; ++j) red[w][j] = acc[j];
    }
    __syncthreads();
    if (t == 0) {
        float f[10];
#pragma unroll
        for (int j = 0; j < 10; ++j) f[j] = red[0][j] + red[1][j] + red[2][j] + red[3][j];
        float s0 = f[0] + cls_b[0], s1 = f[1] + cls_b[1];
        float m = fmaxf(s0, s1);
        float e0 = expf(s0 - m), e1 = expf(s1 - m);
        float inv = 1.0f / (e0 + e1);

        float bx1 = boxes[roi * 4 + 0], by1 = boxes[roi * 4 + 1];
        float bx2 = boxes[roi * 4 + 2], by2 = boxes[roi * 4 + 3];
        float pw = bx2 - bx1, ph = by2 - by1;
        float cx = bx1 + 0.5f * pw, cy = by1 + 0.5f * ph;
        const float CLAMPV = 4.135166556742356f;
        float* orow = out + roi * 10;
#pragma unroll
        for (int cl = 0; cl < 2; ++cl) {
            float dx = (f[2 + cl * 4 + 0] + bbox_b[cl * 4 + 0]) * 0.1f;
            float dy = (f[2 + cl * 4 + 1] + bbox_b[cl * 4 + 1]) * 0.1f;
            float dw = fminf((f[2 + cl * 4 + 2] + bbox_b[cl * 4 + 2]) * 0.2f, CLAMPV);
            float dh = fminf((f[2 + cl * 4 + 3] + bbox_b[cl * 4 + 3]) * 0.2f, CLAMPV);
            float pcx = dx * pw + cx, pcy = dy * ph + cy;
            float pww = expf(dw) * pw, phh = expf(dh) * ph;
            orow[cl * 4 + 0] = fminf(fmaxf(pcx - 0.5f * pww, 0.0f), 1088.0f);
            orow[cl * 4 + 1] = fminf(fmaxf(pcy - 0.5f * phh, 0.0f), 800.0f);
            orow[cl * 4 + 2] = fminf(fmaxf(pcx + 0.5f * pww, 0.0f), 1088.0f);
            orow[cl * 4 + 3] = fminf(fmaxf(pcy + 0.5f * phh, 0.0f), 800.0f);
        }
        orow[8] = e0 * inv;
        orow[9] = e1 * inv;
    }
}

extern "C" void kernel_launch(void* const* d_in, const int* in_sizes, int n_in,
                              void* d_out, int out_size, void* d_ws, size_t ws_size,
                              hipStream_t stream) {
    const float* features = (const float*)d_in[0];
    const float* boxes    = (const float*)d_in[1];
    const int*   roi_b    = (const int*)d_in[2];
    const float* fc1_w    = (const float*)d_in[3];
    const float* fc1_b    = (const float*)d_in[4];
    const float* fc2_w    = (const float*)d_in[5];
    const float* fc2_b    = (const float*)d_in[6];
    const float* cls_w    = (const float*)d_in[7];
    const float* cls_b    = (const float*)d_in[8];
    const float* bbox_w   = (const float*)d_in[9];
    const float* bbox_b   = (const float*)d_in[10];
    float* out = (float*)d_out;

    char* ws = (char*)d_ws;
    BF16* featT = (BF16*)(ws + 0);           // [0, 13,926,400)
    BF16* w1t   = (BF16*)(ws + 13926400);    // [.., 39,616,512)
    BF16* w2t   = (BF16*)(ws + 39616512);    // [.., 41,713,664)
    BF16* feats = (BF16*)(ws + 41713664);    // [.., 67,403,776)
    BF16* h1    = (BF16*)(ws + 67403776);    // [.., 69,500,928)
    float* P1   = (float*)(ws + 69500928);   // 7 * 4 MB -> ends 98,861,056 (ws = 256 MiB)
    float* P2   = (float*)(ws + 0);          // 4 * 4 MB; reuses dead featT region

    int S1 = 7;   // 12544 = 7 * 1792, 1792 = 28 * 64
    int S2 = 4;   // 1024 = 4 * 256, 256 = 4 * 64

    transpose_all<<<20368, 256, 0, stream>>>(features, fc1_w, fc2_w, featT, w1t, w2t);

    roi_align_k<<<1024, 256, 0, stream>>>(featT, boxes, roi_b, feats);

    gemm_splitk<<<dim3(8, 8, S1), 256, 0, stream>>>(feats, w1t, P1, 12544, 12544 / S1);
    reduce_k<<<4096, 256, 0, stream>>>(P1, fc1_b, h1, S1);

    gemm_splitk<<<dim3(8, 8, S2), 256, 0, stream>>>(h1, w2t, P2, 1024, 1024 / S2);

    head_k<<<1000, 256, 0, stream>>>(P2, fc2_b, cls_w, cls_b, bbox_w, bbox_b, boxes, out, S2);
}